// Round 1
// baseline (229.036 us; speedup 1.0000x reference)
//
#include <hip/hip_runtime.h>
#include <math.h>

#define EPS 1e-6f

static constexpr int N = 32768;
static constexpr int K = 2048;
static constexpr int D = 768;          // 768 floats = 192 float4 per row
static constexpr int WAVES_PER_BLOCK = 4;
static constexpr int ROWS_PER_BLOCK = WAVES_PER_BLOCK;  // one wave per row

__global__ void init_ws_kernel(float* ws) {
    ws[0] = 0.0f;
}

// One 64-lane wave per row. Each lane loads 3 float4 (12 floats) of x and of
// the gathered prototype row, accumulates (x - p + EPS)^2, wave-reduces,
// sqrt on lane 0, block-reduce across 4 waves, one atomicAdd per block.
__global__ __launch_bounds__(256) void pos_dist_sum_kernel(
        const float* __restrict__ x,
        const float* __restrict__ proto,
        const int*   __restrict__ labels,
        float* __restrict__ ws) {
    const int wave = threadIdx.x >> 6;          // 0..3
    const int lane = threadIdx.x & 63;
    const int row  = blockIdx.x * ROWS_PER_BLOCK + wave;

    float wave_out = 0.0f;
    if (row < N) {
        const int lbl = labels[row];
        const float4* __restrict__ xr = (const float4*)(x     + (size_t)row * D);
        const float4* __restrict__ pr = (const float4*)(proto + (size_t)lbl * D);

        float acc = 0.0f;
        #pragma unroll
        for (int j = 0; j < 3; ++j) {
            const int idx = j * 64 + lane;      // coalesced float4 across the wave
            float4 a = xr[idx];
            float4 b = pr[idx];
            float d0 = a.x - b.x + EPS;
            float d1 = a.y - b.y + EPS;
            float d2 = a.z - b.z + EPS;
            float d3 = a.w - b.w + EPS;
            acc = fmaf(d0, d0, acc);
            acc = fmaf(d1, d1, acc);
            acc = fmaf(d2, d2, acc);
            acc = fmaf(d3, d3, acc);
        }
        // 64-lane butterfly reduce
        #pragma unroll
        for (int off = 32; off > 0; off >>= 1)
            acc += __shfl_down(acc, off, 64);
        if (lane == 0) wave_out = sqrtf(acc);
    }

    __shared__ float red[WAVES_PER_BLOCK];
    if (lane == 0) red[wave] = wave_out;
    __syncthreads();
    if (threadIdx.x == 0) {
        float s = 0.0f;
        #pragma unroll
        for (int w = 0; w < WAVES_PER_BLOCK; ++w) s += red[w];
        atomicAdd(ws, s);                        // device-scope by default
    }
}

// loss = pos_dist.sum()/N  +  (1/inf)/N  == pos_dist.sum()/N
__global__ void finalize_kernel(const float* __restrict__ ws,
                                float* __restrict__ out) {
    out[0] = ws[0] / (float)N;
}

extern "C" void kernel_launch(void* const* d_in, const int* in_sizes, int n_in,
                              void* d_out, int out_size, void* d_ws, size_t ws_size,
                              hipStream_t stream) {
    const float* x      = (const float*)d_in[0];   // [N, D] fp32
    const float* proto  = (const float*)d_in[1];   // [K, D] fp32
    const int*   labels = (const int*)d_in[2];     // [N] int
    float* out = (float*)d_out;
    float* ws  = (float*)d_ws;

    (void)in_sizes; (void)n_in; (void)out_size; (void)ws_size;

    init_ws_kernel<<<1, 1, 0, stream>>>(ws);

    const int grid = N / ROWS_PER_BLOCK;           // 8192 blocks
    pos_dist_sum_kernel<<<grid, 256, 0, stream>>>(x, proto, labels, ws);

    finalize_kernel<<<1, 1, 0, stream>>>(ws, out);
}

// Round 2
// 153.288 us; speedup vs baseline: 1.4942x; 1.4942x over previous
//
#include <hip/hip_runtime.h>
#include <math.h>

#define EPS 1e-6f

static constexpr int N = 32768;
static constexpr int K = 2048;
static constexpr int D = 768;          // 768 floats = 192 float4 per row
static constexpr int WAVES_PER_BLOCK = 4;
static constexpr int ROWS_PER_BLOCK = WAVES_PER_BLOCK;   // one wave per row
static constexpr int GRID1 = N / ROWS_PER_BLOCK;         // 8192 blocks

// Stage 1: one 64-lane wave per row. Each lane loads 3 float4 (12 floats) of
// x and of the gathered prototype row, accumulates (x - p + EPS)^2,
// wave-reduces, sqrt on lane 0, block-reduce across 4 waves, ONE PLAIN STORE
// per block into the partials array (no atomics — 8192 same-address atomics
// serialized at ~33 cyc each was the entire 113 us of round 1).
__global__ __launch_bounds__(256) void pos_dist_partial_kernel(
        const float* __restrict__ x,
        const float* __restrict__ proto,
        const int*   __restrict__ labels,
        float* __restrict__ partials) {
    const int wave = threadIdx.x >> 6;          // 0..3
    const int lane = threadIdx.x & 63;
    const int row  = blockIdx.x * ROWS_PER_BLOCK + wave;

    // Issue the label load first so its latency overlaps the x loads.
    const int lbl = labels[row];

    const float4* __restrict__ xr = (const float4*)(x     + (size_t)row * D);
    const float4* __restrict__ pr = (const float4*)(proto + (size_t)lbl * D);

    float acc = 0.0f;
    #pragma unroll
    for (int j = 0; j < 3; ++j) {
        const int idx = j * 64 + lane;          // coalesced float4 across the wave
        float4 a = xr[idx];
        float4 b = pr[idx];
        float d0 = a.x - b.x + EPS;
        float d1 = a.y - b.y + EPS;
        float d2 = a.z - b.z + EPS;
        float d3 = a.w - b.w + EPS;
        acc = fmaf(d0, d0, acc);
        acc = fmaf(d1, d1, acc);
        acc = fmaf(d2, d2, acc);
        acc = fmaf(d3, d3, acc);
    }
    // 64-lane butterfly reduce
    #pragma unroll
    for (int off = 32; off > 0; off >>= 1)
        acc += __shfl_down(acc, off, 64);

    __shared__ float red[WAVES_PER_BLOCK];
    if (lane == 0) red[wave] = sqrtf(acc);
    __syncthreads();
    if (threadIdx.x == 0) {
        float s = 0.0f;
        #pragma unroll
        for (int w = 0; w < WAVES_PER_BLOCK; ++w) s += red[w];
        partials[blockIdx.x] = s;               // plain store, no contention
    }
}

// Stage 2: one 256-thread block reduces GRID1 partials; out = sum / N.
// (1/neg_dists.sum() term is exactly 0: one inf per row makes the sum inf.)
__global__ __launch_bounds__(256) void reduce_finalize_kernel(
        const float* __restrict__ partials,
        float* __restrict__ out) {
    const int tid = threadIdx.x;
    const float4* p4 = (const float4*)partials;
    constexpr int NV4 = GRID1 / 4;              // 2048 float4

    float acc = 0.0f;
    for (int i = tid; i < NV4; i += 256) {
        float4 v = p4[i];
        acc += v.x + v.y + v.z + v.w;
    }
    #pragma unroll
    for (int off = 32; off > 0; off >>= 1)
        acc += __shfl_down(acc, off, 64);

    __shared__ float red[4];
    const int wave = tid >> 6;
    const int lane = tid & 63;
    if (lane == 0) red[wave] = acc;
    __syncthreads();
    if (tid == 0) {
        float s = red[0] + red[1] + red[2] + red[3];
        out[0] = s / (float)N;
    }
}

extern "C" void kernel_launch(void* const* d_in, const int* in_sizes, int n_in,
                              void* d_out, int out_size, void* d_ws, size_t ws_size,
                              hipStream_t stream) {
    const float* x      = (const float*)d_in[0];   // [N, D] fp32
    const float* proto  = (const float*)d_in[1];   // [K, D] fp32
    const int*   labels = (const int*)d_in[2];     // [N] int
    float* out      = (float*)d_out;
    float* partials = (float*)d_ws;                // GRID1 floats (32 KB < ws)

    (void)in_sizes; (void)n_in; (void)out_size; (void)ws_size;

    pos_dist_partial_kernel<<<GRID1, 256, 0, stream>>>(x, proto, labels, partials);
    reduce_finalize_kernel<<<1, 256, 0, stream>>>(partials, out);
}